// Round 5
// baseline (98514.050 us; speedup 1.0000x reference)
//
#include <hip/hip_runtime.h>
#include <hip/hip_bf16.h>

// Problem constants
#define SEQ  256
#define BSZ  128
#define DM   512
#define HID  1536
#define KTOT 2560      // x(512) | r(512) | h(1536)
#define VC   6144      // virtual cols: [0,3072) fused rz, [3072,4608) inn, [4608,6144) hn
#define NBLK 720       // persistent grid

typedef __attribute__((ext_vector_type(4))) float f32x4;
typedef __attribute__((ext_vector_type(8))) short short8;
typedef __attribute__((ext_vector_type(4))) unsigned short us4;
typedef __attribute__((ext_vector_type(8))) unsigned short us8;

// ws layout (bytes)
#define OFF_WBH 0ull                 // bf16 [4608][2560] hi   = 23,592,960
#define OFF_WBL 23592960ull          // bf16 [4608][2560] lo   = 23,592,960
#define OFF_P   47185920ull          // f32  [5][128][6144]    = 15,728,640
#define OFF_R32 62914560ull          // f32  [128][512]        =    262,144
#define OFF_A   63176704ull          // f32  [1024][64][64]    = 16,777,216   (zeroed in-kernel)
#define OFF_H32 79953920ull          // f32  [128][1536]       =    786,432   (zeroed)
#define OFF_RBH 80740352ull          // bf16 [128][512]  hi    (zeroed)
#define OFF_RBL 80871424ull          // bf16 [128][512]  lo    (zeroed)
#define OFF_HBH 81002496ull          // bf16 [128][1536] hi    (zeroed)
#define OFF_HBL 81395712ull          // bf16 [128][1536] lo    (zeroed)
#define OFF_BAR 81788928ull          // barrier: 64 uints (cnt @0, epoch @32), zeroed by pk_wb
// in-kernel zero region: OFF_A..OFF_BAR = 18,612,224 B = 1,163,264 x 16B

static __device__ __forceinline__ unsigned short bf(float x) {
  __hip_bfloat16 h = __float2bfloat16(x);
  return *reinterpret_cast<unsigned short*>(&h);
}
static __device__ __forceinline__ float bf2f(unsigned short u) {
  union { unsigned int i; float f; } c; c.i = ((unsigned int)u) << 16;
  return c.f;
}

// ---------------- grid-wide barrier (sense-reversing, agent scope) ----------------
static __device__ __forceinline__ void gsync(unsigned* cnt, unsigned* ep) {
  __syncthreads();
  if (threadIdx.x == 0) {
    __threadfence();   // publish this block's writes (agent scope)
    unsigned e = __hip_atomic_load(ep, __ATOMIC_ACQUIRE, __HIP_MEMORY_SCOPE_AGENT);
    if (atomicAdd(cnt, 1u) == NBLK - 1u) {
      __hip_atomic_store(cnt, 0u, __ATOMIC_RELAXED, __HIP_MEMORY_SCOPE_AGENT);
      __threadfence();
      atomicAdd(ep, 1u);
    } else {
      while (__hip_atomic_load(ep, __ATOMIC_ACQUIRE, __HIP_MEMORY_SCOPE_AGENT) == e)
        __builtin_amdgcn_s_sleep(2);
    }
    __threadfence();   // acquire: see other XCDs' writes
  }
  __syncthreads();
}

// ---------------- prep: repack weights to hi/lo bf16 [4608][2560]; zero barrier ----------------
__global__ __launch_bounds__(256) void pk_wb(const float* __restrict__ Wih,
                                             const float* __restrict__ Whh,
                                             unsigned short* __restrict__ Wh,
                                             unsigned short* __restrict__ Wl,
                                             unsigned* __restrict__ bar) {
  if (blockIdx.x == 0 && threadIdx.x < 64) bar[threadIdx.x] = 0u;
  int idx = blockIdx.x * 256 + threadIdx.x;        // < 4608*640 = 2,949,120
  int row = idx / 640;
  int k = (idx - row * 640) * 4;
  const float* src = (k < 1024) ? (Wih + (size_t)row * 1024 + k)
                                : (Whh + (size_t)row * HID + (k - 1024));
  f32x4 v = *(const f32x4*)src;
  us4 oh, ol;
#pragma unroll
  for (int i = 0; i < 4; ++i) {
    unsigned short h = bf(v[i]);
    oh[i] = h;
    ol[i] = bf(v[i] - bf2f(h));
  }
  *(us4*)(Wh + (size_t)row * KTOT + k) = oh;
  *(us4*)(Wl + (size_t)row * KTOT + k) = ol;
}

// ---------------- persistent fused kernel: init + 256 x (GEMM | pair) ----------------
// 720 blocks x 256 threads. GEMM tasks: 720 = rz 96jg*5ks + inn 48jg*2ks + hn 48jg*3ks,
// each task = [128 b x 32 cols], K-chunk 512, hi/lo 3-term MFMA.
__global__ __launch_bounds__(256, 3) void fused(
    const float* __restrict__ x, const float* __restrict__ bih,
    const float* __restrict__ bhh, char* __restrict__ ws,
    float* __restrict__ dout)
{
  const unsigned short* Wh  = (const unsigned short*)(ws + OFF_WBH);
  const unsigned short* Wl  = (const unsigned short*)(ws + OFF_WBL);
  float*          P   = (float*)(ws + OFF_P);
  float*          r32 = (float*)(ws + OFF_R32);
  float*          A   = (float*)(ws + OFF_A);
  float*          h32 = (float*)(ws + OFF_H32);
  unsigned short* Rbh = (unsigned short*)(ws + OFF_RBH);
  unsigned short* Rbl = (unsigned short*)(ws + OFF_RBL);
  unsigned short* Hbh = (unsigned short*)(ws + OFF_HBH);
  unsigned short* Hbl = (unsigned short*)(ws + OFF_HBL);
  unsigned* cnt = (unsigned*)(ws + OFF_BAR);
  unsigned* ep  = (unsigned*)(ws + OFF_BAR + 128);

  const int blk = blockIdx.x;
  const int tid = threadIdx.x;

  // ---- init: zero A, h32, Rb*, Hb* ----
  {
    f32x4* z4 = (f32x4*)(ws + OFF_A);
    f32x4 z = {0.f, 0.f, 0.f, 0.f};
    for (size_t i = (size_t)blk * 256 + tid; i < 1163264ull; i += (size_t)NBLK * 256)
      z4[i] = z;
  }
  gsync(cnt, ep);

  // ---- static GEMM task decode (all 720 blocks valid) ----
  int jg, ks;
  if (blk < 480)      { jg = blk / 5;              ks = blk % 5; }
  else if (blk < 576) { int u = blk - 480; jg = 96  + u / 2; ks = u % 2; }
  else                { int u = blk - 576; jg = 144 + u / 3; ks = 2 + u % 3; }
  const int colb  = jg * 32;
  const int wrowb = (jg < 144 ? colb : colb - 1536);   // inn/hn share W rows [3072,4608)
  const int kc0   = ks * 512;

  const int wave = tid >> 6, lane = tid & 63;
  const int bh  = (wave & 1) * 64;        // b-half base
  const int jh  = (wave >> 1) * 16;       // col-16 base within the 32-col tile
  const int l15 = lane & 15, kg = lane >> 4;
  const int sr_ = tid >> 1;               // staging row 0..127
  const int sc_ = (tid & 1) * 16;         // staging col 0 or 16
  const int wrow0 = wrowb + jh;

  __shared__ __align__(16) unsigned short AH[128 * 40];
  __shared__ __align__(16) unsigned short AL[128 * 40];
  __shared__ __align__(16) float kS[4][64];
  __shared__ __align__(16) float qS[4][64];

  for (int t = 0; t < SEQ; ++t) {
    // ================= GEMM phase =================
    f32x4 acc[4];
#pragma unroll
    for (int i = 0; i < 4; ++i) acc[i] = (f32x4){0.f, 0.f, 0.f, 0.f};

    for (int it = 0; it < 16; ++it) {
      int kabs = kc0 + it * 32;
      us8 h0, h1, l0, l1;
      if (ks == 0) {           // K [0,512): x (f32 -> hi/lo bf16)
        const float* p = x + ((size_t)t * BSZ + sr_) * DM + kabs + sc_;
        f32x4 f0 = ((const f32x4*)p)[0];
        f32x4 f1 = ((const f32x4*)p)[1];
        f32x4 f2 = ((const f32x4*)p)[2];
        f32x4 f3 = ((const f32x4*)p)[3];
#pragma unroll
        for (int i = 0; i < 4; ++i) {
          unsigned short hh = bf(f0[i]); h0[i]     = hh; l0[i]     = bf(f0[i] - bf2f(hh));
          hh = bf(f1[i]);                h0[4 + i] = hh; l0[4 + i] = bf(f1[i] - bf2f(hh));
          hh = bf(f2[i]);                h1[i]     = hh; l1[i]     = bf(f2[i] - bf2f(hh));
          hh = bf(f3[i]);                h1[4 + i] = hh; l1[4 + i] = bf(f3[i] - bf2f(hh));
        }
      } else if (ks == 1) {    // K [512,1024): r (bf16 hi/lo)
        size_t off = (size_t)sr_ * DM + (kabs - 512) + sc_;
        h0 = *(const us8*)(Rbh + off); h1 = *(const us8*)(Rbh + off + 8);
        l0 = *(const us8*)(Rbl + off); l1 = *(const us8*)(Rbl + off + 8);
      } else {                 // K [1024,2560): h (bf16 hi/lo)
        size_t off = (size_t)sr_ * HID + (kabs - 1024) + sc_;
        h0 = *(const us8*)(Hbh + off); h1 = *(const us8*)(Hbh + off + 8);
        l0 = *(const us8*)(Hbl + off); l1 = *(const us8*)(Hbl + off + 8);
      }
      __syncthreads();
      *(us8*)&AH[sr_ * 40 + sc_]     = h0;
      *(us8*)&AH[sr_ * 40 + sc_ + 8] = h1;
      *(us8*)&AL[sr_ * 40 + sc_]     = l0;
      *(us8*)&AL[sr_ * 40 + sc_ + 8] = l1;
      __syncthreads();

      size_t woff = (size_t)(wrow0 + l15) * KTOT + kabs + kg * 8;
      short8 wh_ = *(const short8*)(Wh + woff);
      short8 wl_ = *(const short8*)(Wl + woff);
#pragma unroll
      for (int bt = 0; bt < 4; ++bt) {
        short8 ah = *(const short8*)&AH[(bh + bt * 16 + l15) * 40 + kg * 8];
        short8 al = *(const short8*)&AL[(bh + bt * 16 + l15) * 40 + kg * 8];
        acc[bt] = __builtin_amdgcn_mfma_f32_16x16x32_bf16(ah, wh_, acc[bt], 0, 0, 0);
        acc[bt] = __builtin_amdgcn_mfma_f32_16x16x32_bf16(ah, wl_, acc[bt], 0, 0, 0);
        acc[bt] = __builtin_amdgcn_mfma_f32_16x16x32_bf16(al, wh_, acc[bt], 0, 0, 0);
      }
    }
#pragma unroll
    for (int bt = 0; bt < 4; ++bt)
#pragma unroll
      for (int i = 0; i < 4; ++i)
        P[((size_t)ks * BSZ + bh + bt * 16 + kg * 4 + i) * VC + colb + jh + l15] = acc[bt][i];

    gsync(cnt, ep);

    // ================= pair phase (blocks 0..255, 4 pairs each) =================
    if (blk < 256) {
      int pw = tid >> 6;
      int pair = blk * 4 + pw;
      int b = pair >> 3, n = pair & 7;
      int l = lane;
      const float* Pb = P + (size_t)b * VC;
      float hv[3];
#pragma unroll
      for (int s = 0; s < 3; ++s) {
        int c = s * 512 + n * 64 + l;
        float sr2 = 0.f, sz = 0.f;
#pragma unroll
        for (int ksi = 0; ksi < 5; ++ksi) {
          const float* q = Pb + (size_t)ksi * BSZ * VC;
          sr2 += q[c];
          sz  += q[1536 + c];
        }
        float gin = Pb[3072 + c] + Pb[(size_t)BSZ * VC + 3072 + c];
        float ghn = 0.f;
#pragma unroll
        for (int ksi = 2; ksi < 5; ++ksi) ghn += Pb[(size_t)ksi * BSZ * VC + 4608 + c];
        float rg = 1.f / (1.f + __expf(-(sr2 + bih[c] + bhh[c])));
        float zg = 1.f / (1.f + __expf(-(sz + bih[1536 + c] + bhh[1536 + c])));
        float nn = tanhf(gin + bih[3072 + c] + rg * (ghn + bhh[3072 + c]));
        size_t hix = (size_t)b * HID + c;
        float hp = h32[hix];
        float hnew = (1.f - zg) * nn + zg * hp;
        h32[hix] = hnew;
        unsigned short hh2 = bf(hnew);
        Hbh[hix] = hh2;
        Hbl[hix] = bf(hnew - bf2f(hh2));
        hv[s] = hnew;
      }
      float ssq = hv[0] * hv[0], ssk = hv[1] * hv[1];
#pragma unroll
      for (int off = 32; off > 0; off >>= 1) {
        ssq += __shfl_xor(ssq, off);
        ssk += __shfl_xor(ssk, off);
      }
      float qn = hv[0] * rsqrtf(ssq);
      float kn = hv[1] * rsqrtf(ssk);
      float ke = kn > 0.f ? kn : expm1f(kn);   // elu(unitnorm)
      kS[pw][l] = ke;
      qS[pw][l] = qn;       // wave-local LDS: no cross-wave sharing -> no __syncthreads

      float vvl = hv[2];
      float* Arow = A + ((size_t)pair * 64 + l) * 64;
      float racc = 0.f;
#pragma unroll
      for (int q4 = 0; q4 < 16; ++q4) {
        f32x4 a  = *(f32x4*)(Arow + q4 * 4);
        f32x4 kk = *(f32x4*)&kS[pw][q4 * 4];
        f32x4 qq = *(f32x4*)&qS[pw][q4 * 4];
        a[0] += kk[0] * vvl; a[1] += kk[1] * vvl;
        a[2] += kk[2] * vvl; a[3] += kk[3] * vvl;
        racc += qq[0] * a[0] + qq[1] * a[1] + qq[2] * a[2] + qq[3] * a[3];
        *(f32x4*)(Arow + q4 * 4) = a;
      }
      size_t ri = (size_t)b * DM + n * 64 + l;
      r32[ri] = racc;
      unsigned short rh2 = bf(racc);
      Rbh[ri] = rh2;
      Rbl[ri] = bf(racc - bf2f(rh2));

      if (t == SEQ - 1) {
        dout[65536  + pair * 64 + l] = ke;   // k output (f32)
        dout[131072 + pair * 64 + l] = qn;   // q output (f32)
      }
    }
    gsync(cnt, ep);
  }
}

// ---------------- final: out = r @ Wo.T + bo (f32) ----------------
__global__ __launch_bounds__(512) void out_gemm(const float* __restrict__ r32,
                                                const float* __restrict__ Wo,
                                                const float* __restrict__ bo,
                                                float* __restrict__ dout) {
  int b0 = blockIdx.x * 2;
  int o  = threadIdx.x;
  __shared__ float rL0[512];
  __shared__ float rL1[512];
  rL0[o] = r32[(size_t)b0 * DM + o];
  rL1[o] = r32[(size_t)(b0 + 1) * DM + o];
  __syncthreads();
  float a0 = bo[o], a1 = a0;
  const float* wrow = Wo + (size_t)o * DM;
  for (int c = 0; c < DM; ++c) {
    float w = wrow[c];
    a0 += rL0[c] * w;
    a1 += rL1[c] * w;
  }
  dout[(size_t)b0 * DM + o]       = a0;
  dout[(size_t)(b0 + 1) * DM + o] = a1;
}

extern "C" void kernel_launch(void* const* d_in, const int* in_sizes, int n_in,
                              void* d_out, int out_size, void* d_ws, size_t ws_size,
                              hipStream_t stream) {
  // Defensive input identification by element count (deterministic).
  int ix = 0, iwih = 1, iwhh = 2, ibih = 3, ibhh = 4, iwo = 5, ibo = 6;
  {
    int b1 = -1, b2 = -1;
    for (int i = 0; i < n_in; ++i) {
      int s = in_sizes[i];
      if      (s == SEQ * BSZ * DM) ix = i;
      else if (s == 4608 * 1024)    iwih = i;
      else if (s == 4608 * 1536)    iwhh = i;
      else if (s == DM * DM)        iwo = i;
      else if (s == DM)             ibo = i;
      else if (s == 4608)           { if (b1 < 0) b1 = i; else b2 = i; }
    }
    if (b1 >= 0) ibih = b1;
    if (b2 >= 0) ibhh = b2;
  }
  const float* x   = (const float*)d_in[ix];
  const float* Wih = (const float*)d_in[iwih];
  const float* Whh = (const float*)d_in[iwhh];
  const float* bih = (const float*)d_in[ibih];
  const float* bhh = (const float*)d_in[ibhh];
  const float* Wo  = (const float*)d_in[iwo];
  const float* bo  = (const float*)d_in[ibo];

  char* ws = (char*)d_ws;
  unsigned short* Wh  = (unsigned short*)(ws + OFF_WBH);
  unsigned short* Wl  = (unsigned short*)(ws + OFF_WBL);
  float*          r32 = (float*)(ws + OFF_R32);
  unsigned*       bar = (unsigned*)(ws + OFF_BAR);
  float* dout = (float*)d_out;

  pk_wb<<<11520, 256, 0, stream>>>(Wih, Whh, Wh, Wl, bar);
  fused<<<NBLK, 256, 0, stream>>>(x, bih, bhh, ws, dout);
  out_gemm<<<64, 512, 0, stream>>>(r32, Wo, bo, dout);
}

// Round 6
// 32216.675 us; speedup vs baseline: 3.0579x; 3.0579x over previous
//
#include <hip/hip_runtime.h>
#include <hip/hip_bf16.h>

// Problem constants
#define SEQ  256
#define BSZ  128
#define DM   512
#define HID  1536
#define KTOT 2560      // x(512) | r(512) | h(1536)
#define VC   6144      // virtual cols: [0,3072) fused rz, [3072,4608) inn, [4608,6144) hn
#define NBLK 720       // persistent grid = 45 groups x 16

typedef __attribute__((ext_vector_type(4))) float f32x4;
typedef __attribute__((ext_vector_type(8))) short short8;
typedef __attribute__((ext_vector_type(4))) unsigned short us4;
typedef __attribute__((ext_vector_type(8))) unsigned short us8;

// ws layout (bytes)
#define OFF_WBH 0ull                 // bf16 [4608][2560] hi   = 23,592,960
#define OFF_WBL 23592960ull          // bf16 [4608][2560] lo   = 23,592,960
#define OFF_P   47185920ull          // f32  [5][128][6144]    = 15,728,640
#define OFF_R32 62914560ull          // f32  [128][512]        =    262,144
#define OFF_A   63176704ull          // f32  [1024][64][64]    = 16,777,216   (zeroed in-kernel)
#define OFF_H32 79953920ull          // f32  [128][1536]       =    786,432   (zeroed)
#define OFF_RBH 80740352ull          // bf16 [128][512]  hi    (zeroed)
#define OFF_RBL 80871424ull          // bf16 [128][512]  lo    (zeroed)
#define OFF_HBH 81002496ull          // bf16 [128][1536] hi    (zeroed)
#define OFF_HBL 81395712ull          // bf16 [128][1536] lo    (zeroed)
#define OFF_BAR 81788928ull          // barrier: 1024 uints (root@0, ep@32, gcnt[g]@64+g*16)
// in-kernel zero region: OFF_A..OFF_BAR = 18,612,224 B = 1,163,264 x 16B

static __device__ __forceinline__ unsigned short bf(float x) {
  __hip_bfloat16 h = __float2bfloat16(x);
  return *reinterpret_cast<unsigned short*>(&h);
}
static __device__ __forceinline__ float bf2f(unsigned short u) {
  union { unsigned int i; float f; } c; c.i = ((unsigned int)u) << 16;
  return c.f;
}

// ---------------- grid barrier v2: RMW arrivals + SYSTEM-scope polls ----------------
// All cross-XCD state changes are atomic RMWs (execute at the coherence point);
// polling loads are SYSTEM scope (sc0|sc1: bypass L1+L2, read LLC) so remote epoch
// flips are observed in ~LLC latency instead of waiting for an L2 eviction.
static __device__ __forceinline__ unsigned sysld(unsigned* p) {
  return __hip_atomic_load(p, __ATOMIC_RELAXED, __HIP_MEMORY_SCOPE_SYSTEM);
}
static __device__ __forceinline__ void gsync(unsigned* bar) {
  __syncthreads();
  if (threadIdx.x == 0) {
    unsigned* root = bar;                                  // 45-way
    unsigned* ep   = bar + 32;                             // epoch
    unsigned* gcnt = bar + 64 + (blockIdx.x >> 4) * 16;    // per-group line (64B)
    __threadfence();                         // release this block's writes
    unsigned e = sysld(ep);                  // read epoch BEFORE arriving
    if (atomicAdd(gcnt, 1u) == 15u) {        // group complete
      atomicSub(gcnt, 16u);                  // reset via RMW (coherent)
      __threadfence();
      if (atomicAdd(root, 1u) == 44u) {      // grid complete
        atomicSub(root, 45u);
        __threadfence();
        atomicAdd(ep, 1u);                   // flip epoch
      }
    }
    while (sysld(ep) == e) __builtin_amdgcn_s_sleep(8);
    __threadfence();                         // acquire other blocks' writes
  }
  __syncthreads();
}

// ---------------- prep: repack weights to hi/lo bf16 [4608][2560]; zero barrier ----------------
__global__ __launch_bounds__(256) void pk_wb(const float* __restrict__ Wih,
                                             const float* __restrict__ Whh,
                                             unsigned short* __restrict__ Wh,
                                             unsigned short* __restrict__ Wl,
                                             unsigned* __restrict__ bar) {
  if (blockIdx.x == 0)
    for (int i = threadIdx.x; i < 1024; i += 256) bar[i] = 0u;
  int idx = blockIdx.x * 256 + threadIdx.x;        // < 4608*640 = 2,949,120
  int row = idx / 640;
  int k = (idx - row * 640) * 4;
  const float* src = (k < 1024) ? (Wih + (size_t)row * 1024 + k)
                                : (Whh + (size_t)row * HID + (k - 1024));
  f32x4 v = *(const f32x4*)src;
  us4 oh, ol;
#pragma unroll
  for (int i = 0; i < 4; ++i) {
    unsigned short h = bf(v[i]);
    oh[i] = h;
    ol[i] = bf(v[i] - bf2f(h));
  }
  *(us4*)(Wh + (size_t)row * KTOT + k) = oh;
  *(us4*)(Wl + (size_t)row * KTOT + k) = ol;
}

// ---------------- persistent fused kernel: init + 256 x (GEMM | pair) ----------------
// 720 blocks x 256 threads. GEMM tasks: 720 = rz 96jg*5ks + inn 48jg*2ks + hn 48jg*3ks,
// each task = [128 b x 32 cols], K-chunk 512, hi/lo 3-term MFMA.
__global__ __launch_bounds__(256, 3) void fused(
    const float* __restrict__ x, const float* __restrict__ bih,
    const float* __restrict__ bhh, char* __restrict__ ws,
    float* __restrict__ dout)
{
  const unsigned short* Wh  = (const unsigned short*)(ws + OFF_WBH);
  const unsigned short* Wl  = (const unsigned short*)(ws + OFF_WBL);
  float*          P   = (float*)(ws + OFF_P);
  float*          r32 = (float*)(ws + OFF_R32);
  float*          A   = (float*)(ws + OFF_A);
  float*          h32 = (float*)(ws + OFF_H32);
  unsigned short* Rbh = (unsigned short*)(ws + OFF_RBH);
  unsigned short* Rbl = (unsigned short*)(ws + OFF_RBL);
  unsigned short* Hbh = (unsigned short*)(ws + OFF_HBH);
  unsigned short* Hbl = (unsigned short*)(ws + OFF_HBL);
  unsigned* bar = (unsigned*)(ws + OFF_BAR);

  const int blk = blockIdx.x;
  const int tid = threadIdx.x;

  // ---- init: zero A, h32, Rb*, Hb* ----
  {
    f32x4* z4 = (f32x4*)(ws + OFF_A);
    f32x4 z = {0.f, 0.f, 0.f, 0.f};
    for (size_t i = (size_t)blk * 256 + tid; i < 1163264ull; i += (size_t)NBLK * 256)
      z4[i] = z;
  }
  gsync(bar);

  // ---- static GEMM task decode (all 720 blocks valid) ----
  int jg, ks;
  if (blk < 480)      { jg = blk / 5;              ks = blk % 5; }
  else if (blk < 576) { int u = blk - 480; jg = 96  + u / 2; ks = u % 2; }
  else                { int u = blk - 576; jg = 144 + u / 3; ks = 2 + u % 3; }
  const int colb  = jg * 32;
  const int wrowb = (jg < 144 ? colb : colb - 1536);   // inn/hn share W rows [3072,4608)
  const int kc0   = ks * 512;

  const int wave = tid >> 6, lane = tid & 63;
  const int bh  = (wave & 1) * 64;        // b-half base
  const int jh  = (wave >> 1) * 16;       // col-16 base within the 32-col tile
  const int l15 = lane & 15, kg = lane >> 4;
  const int sr_ = tid >> 1;               // staging row 0..127
  const int sc_ = (tid & 1) * 16;         // staging col 0 or 16
  const int wrow0 = wrowb + jh;

  __shared__ __align__(16) unsigned short AH[128 * 40];
  __shared__ __align__(16) unsigned short AL[128 * 40];
  __shared__ __align__(16) float kS[4][64];
  __shared__ __align__(16) float qS[4][64];

  for (int t = 0; t < SEQ; ++t) {
    // ================= GEMM phase =================
    f32x4 acc[4];
#pragma unroll
    for (int i = 0; i < 4; ++i) acc[i] = (f32x4){0.f, 0.f, 0.f, 0.f};

    for (int it = 0; it < 16; ++it) {
      int kabs = kc0 + it * 32;
      us8 h0, h1, l0, l1;
      if (ks == 0) {           // K [0,512): x (f32 -> hi/lo bf16)
        const float* p = x + ((size_t)t * BSZ + sr_) * DM + kabs + sc_;
        f32x4 f0 = ((const f32x4*)p)[0];
        f32x4 f1 = ((const f32x4*)p)[1];
        f32x4 f2 = ((const f32x4*)p)[2];
        f32x4 f3 = ((const f32x4*)p)[3];
#pragma unroll
        for (int i = 0; i < 4; ++i) {
          unsigned short hh = bf(f0[i]); h0[i]     = hh; l0[i]     = bf(f0[i] - bf2f(hh));
          hh = bf(f1[i]);                h0[4 + i] = hh; l0[4 + i] = bf(f1[i] - bf2f(hh));
          hh = bf(f2[i]);                h1[i]     = hh; l1[i]     = bf(f2[i] - bf2f(hh));
          hh = bf(f3[i]);                h1[4 + i] = hh; l1[4 + i] = bf(f3[i] - bf2f(hh));
        }
      } else if (ks == 1) {    // K [512,1024): r (bf16 hi/lo)
        size_t off = (size_t)sr_ * DM + (kabs - 512) + sc_;
        h0 = *(const us8*)(Rbh + off); h1 = *(const us8*)(Rbh + off + 8);
        l0 = *(const us8*)(Rbl + off); l1 = *(const us8*)(Rbl + off + 8);
      } else {                 // K [1024,2560): h (bf16 hi/lo)
        size_t off = (size_t)sr_ * HID + (kabs - 1024) + sc_;
        h0 = *(const us8*)(Hbh + off); h1 = *(const us8*)(Hbh + off + 8);
        l0 = *(const us8*)(Hbl + off); l1 = *(const us8*)(Hbl + off + 8);
      }
      __syncthreads();
      *(us8*)&AH[sr_ * 40 + sc_]     = h0;
      *(us8*)&AH[sr_ * 40 + sc_ + 8] = h1;
      *(us8*)&AL[sr_ * 40 + sc_]     = l0;
      *(us8*)&AL[sr_ * 40 + sc_ + 8] = l1;
      __syncthreads();

      size_t woff = (size_t)(wrow0 + l15) * KTOT + kabs + kg * 8;
      short8 wh_ = *(const short8*)(Wh + woff);
      short8 wl_ = *(const short8*)(Wl + woff);
#pragma unroll
      for (int bt = 0; bt < 4; ++bt) {
        short8 ah = *(const short8*)&AH[(bh + bt * 16 + l15) * 40 + kg * 8];
        short8 al = *(const short8*)&AL[(bh + bt * 16 + l15) * 40 + kg * 8];
        acc[bt] = __builtin_amdgcn_mfma_f32_16x16x32_bf16(ah, wh_, acc[bt], 0, 0, 0);
        acc[bt] = __builtin_amdgcn_mfma_f32_16x16x32_bf16(ah, wl_, acc[bt], 0, 0, 0);
        acc[bt] = __builtin_amdgcn_mfma_f32_16x16x32_bf16(al, wh_, acc[bt], 0, 0, 0);
      }
    }
#pragma unroll
    for (int bt = 0; bt < 4; ++bt)
#pragma unroll
      for (int i = 0; i < 4; ++i)
        P[((size_t)ks * BSZ + bh + bt * 16 + kg * 4 + i) * VC + colb + jh + l15] = acc[bt][i];

    gsync(bar);

    // ================= pair phase (blocks 0..255, 4 pairs each) =================
    if (blk < 256) {
      int pw = tid >> 6;
      int pair = blk * 4 + pw;
      int b = pair >> 3, n = pair & 7;
      int l = lane;
      const float* Pb = P + (size_t)b * VC;
      float hv[3];
#pragma unroll
      for (int s = 0; s < 3; ++s) {
        int c = s * 512 + n * 64 + l;
        float sr2 = 0.f, sz = 0.f;
#pragma unroll
        for (int ksi = 0; ksi < 5; ++ksi) {
          const float* q = Pb + (size_t)ksi * BSZ * VC;
          sr2 += q[c];
          sz  += q[1536 + c];
        }
        float gin = Pb[3072 + c] + Pb[(size_t)BSZ * VC + 3072 + c];
        float ghn = 0.f;
#pragma unroll
        for (int ksi = 2; ksi < 5; ++ksi) ghn += Pb[(size_t)ksi * BSZ * VC + 4608 + c];
        float rg = 1.f / (1.f + __expf(-(sr2 + bih[c] + bhh[c])));
        float zg = 1.f / (1.f + __expf(-(sz + bih[1536 + c] + bhh[1536 + c])));
        float nn = tanhf(gin + bih[3072 + c] + rg * (ghn + bhh[3072 + c]));
        size_t hix = (size_t)b * HID + c;
        float hp = h32[hix];
        float hnew = (1.f - zg) * nn + zg * hp;
        h32[hix] = hnew;
        unsigned short hh2 = bf(hnew);
        Hbh[hix] = hh2;
        Hbl[hix] = bf(hnew - bf2f(hh2));
        hv[s] = hnew;
      }
      float ssq = hv[0] * hv[0], ssk = hv[1] * hv[1];
#pragma unroll
      for (int off = 32; off > 0; off >>= 1) {
        ssq += __shfl_xor(ssq, off);
        ssk += __shfl_xor(ssk, off);
      }
      float qn = hv[0] * rsqrtf(ssq);
      float kn = hv[1] * rsqrtf(ssk);
      float ke = kn > 0.f ? kn : expm1f(kn);   // elu(unitnorm)
      kS[pw][l] = ke;
      qS[pw][l] = qn;       // wave-local LDS: no cross-wave sharing -> no __syncthreads

      float vvl = hv[2];
      float* Arow = A + ((size_t)pair * 64 + l) * 64;
      float racc = 0.f;
#pragma unroll
      for (int q4 = 0; q4 < 16; ++q4) {
        f32x4 a  = *(f32x4*)(Arow + q4 * 4);
        f32x4 kk = *(f32x4*)&kS[pw][q4 * 4];
        f32x4 qq = *(f32x4*)&qS[pw][q4 * 4];
        a[0] += kk[0] * vvl; a[1] += kk[1] * vvl;
        a[2] += kk[2] * vvl; a[3] += kk[3] * vvl;
        racc += qq[0] * a[0] + qq[1] * a[1] + qq[2] * a[2] + qq[3] * a[3];
        *(f32x4*)(Arow + q4 * 4) = a;
      }
      size_t ri = (size_t)b * DM + n * 64 + l;
      r32[ri] = racc;
      unsigned short rh2 = bf(racc);
      Rbh[ri] = rh2;
      Rbl[ri] = bf(racc - bf2f(rh2));

      if (t == SEQ - 1) {
        dout[65536  + pair * 64 + l] = ke;   // k output (f32)
        dout[131072 + pair * 64 + l] = qn;   // q output (f32)
      }
    }
    gsync(bar);
  }
}

// ---------------- final: out = r @ Wo.T + bo (f32) ----------------
__global__ __launch_bounds__(512) void out_gemm(const float* __restrict__ r32,
                                                const float* __restrict__ Wo,
                                                const float* __restrict__ bo,
                                                float* __restrict__ dout) {
  int b0 = blockIdx.x * 2;
  int o  = threadIdx.x;
  __shared__ float rL0[512];
  __shared__ float rL1[512];
  rL0[o] = r32[(size_t)b0 * DM + o];
  rL1[o] = r32[(size_t)(b0 + 1) * DM + o];
  __syncthreads();
  float a0 = bo[o], a1 = a0;
  const float* wrow = Wo + (size_t)o * DM;
  for (int c = 0; c < DM; ++c) {
    float w = wrow[c];
    a0 += rL0[c] * w;
    a1 += rL1[c] * w;
  }
  dout[(size_t)b0 * DM + o]       = a0;
  dout[(size_t)(b0 + 1) * DM + o] = a1;
}

extern "C" void kernel_launch(void* const* d_in, const int* in_sizes, int n_in,
                              void* d_out, int out_size, void* d_ws, size_t ws_size,
                              hipStream_t stream) {
  // Defensive input identification by element count (deterministic).
  int ix = 0, iwih = 1, iwhh = 2, ibih = 3, ibhh = 4, iwo = 5, ibo = 6;
  {
    int b1 = -1, b2 = -1;
    for (int i = 0; i < n_in; ++i) {
      int s = in_sizes[i];
      if      (s == SEQ * BSZ * DM) ix = i;
      else if (s == 4608 * 1024)    iwih = i;
      else if (s == 4608 * 1536)    iwhh = i;
      else if (s == DM * DM)        iwo = i;
      else if (s == DM)             ibo = i;
      else if (s == 4608)           { if (b1 < 0) b1 = i; else b2 = i; }
    }
    if (b1 >= 0) ibih = b1;
    if (b2 >= 0) ibhh = b2;
  }
  const float* x   = (const float*)d_in[ix];
  const float* Wih = (const float*)d_in[iwih];
  const float* Whh = (const float*)d_in[iwhh];
  const float* bih = (const float*)d_in[ibih];
  const float* bhh = (const float*)d_in[ibhh];
  const float* Wo  = (const float*)d_in[iwo];
  const float* bo  = (const float*)d_in[ibo];

  char* ws = (char*)d_ws;
  unsigned short* Wh  = (unsigned short*)(ws + OFF_WBH);
  unsigned short* Wl  = (unsigned short*)(ws + OFF_WBL);
  float*          r32 = (float*)(ws + OFF_R32);
  unsigned*       bar = (unsigned*)(ws + OFF_BAR);
  float* dout = (float*)d_out;

  pk_wb<<<11520, 256, 0, stream>>>(Wih, Whh, Wh, Wl, bar);
  fused<<<NBLK, 256, 0, stream>>>(x, bih, bhh, ws, dout);
  out_gemm<<<64, 512, 0, stream>>>(r32, Wo, bo, dout);
}